// Round 1
// baseline (1341.294 us; speedup 1.0000x reference)
//
#include <hip/hip_runtime.h>

#define NROWS 2048      // S*N rows of the token matrix
#define NN    1024      // sequence length
#define DIMM  768
#define HEADS 16
#define CH    48        // per-head dim
#define CPAIR 128
#define NSTRIP 16       // gemm column strip per thread
#define KSPLIT 4        // attention k-range split
#define KCH   16        // attention k chunk

__device__ __forceinline__ float sigm(float x){ return 1.0f/(1.0f+__expf(-x)); }

// ---------------------------------------------------------------------------
// LayerNorm of single_repr (no affine) and single_proj (scale-only)
// ---------------------------------------------------------------------------
__global__ __launch_bounds__(256) void k_ln_single(
    const float* __restrict__ srep, const float* __restrict__ sproj,
    const float* __restrict__ sw, float* __restrict__ a_ln, float* __restrict__ s_ln)
{
    int r = blockIdx.x, t = threadIdx.x;
    const float* xa = srep  + (size_t)r*DIMM;
    const float* xs = sproj + (size_t)r*DIMM;
    float va[3], vs[3];
    float sa=0.f,qa=0.f,ss=0.f,qs=0.f;
    #pragma unroll
    for (int i=0;i<3;i++){ float x=xa[t+256*i]; va[i]=x; sa+=x; qa+=x*x; }
    #pragma unroll
    for (int i=0;i<3;i++){ float x=xs[t+256*i]; vs[i]=x; ss+=x; qs+=x*x; }
    #pragma unroll
    for (int off=32; off>=1; off>>=1){
        sa += __shfl_xor(sa,off); qa += __shfl_xor(qa,off);
        ss += __shfl_xor(ss,off); qs += __shfl_xor(qs,off);
    }
    __shared__ float red[16];
    int w = t>>6;
    if ((t&63)==0){ red[w*4+0]=sa; red[w*4+1]=qa; red[w*4+2]=ss; red[w*4+3]=qs; }
    __syncthreads();
    sa = red[0]+red[4]+red[8]+red[12];
    qa = red[1]+red[5]+red[9]+red[13];
    ss = red[2]+red[6]+red[10]+red[14];
    qs = red[3]+red[7]+red[11]+red[15];
    float mua=sa*(1.f/768.f), mus=ss*(1.f/768.f);
    float rva=rsqrtf(fmaxf(qa*(1.f/768.f)-mua*mua,0.f)+1e-5f);
    float rvs=rsqrtf(fmaxf(qs*(1.f/768.f)-mus*mus,0.f)+1e-5f);
    #pragma unroll
    for (int i=0;i<3;i++){
        int c=t+256*i;
        a_ln[(size_t)r*DIMM+c]=(va[i]-mua)*rva;
        s_ln[(size_t)r*DIMM+c]=(vs[i]-mus)*rvs*sw[c];
    }
}

// ---------------------------------------------------------------------------
// pair bias precompute: wpc[c][h] = ln_w[c]*w_pair[c][h];
// csb[h] = sum_c wpc[c][h]; csb[16+h] = sum_c ln_b[c]*w_pair[c][h]
// ---------------------------------------------------------------------------
__global__ void k_pair_pre(const float* __restrict__ lnw, const float* __restrict__ lnb,
                           const float* __restrict__ wp, float* __restrict__ wpc,
                           float* __restrict__ csb)
{
    int t = threadIdx.x;
    for (int i=t;i<2048;i+=256) wpc[i] = lnw[i>>4]*wp[i];
    if (t<16){
        float cs=0.f,b0=0.f;
        for (int c=0;c<128;c++){ cs += lnw[c]*wp[c*16+t]; b0 += lnb[c]*wp[c*16+t]; }
        csb[t]=cs; csb[16+t]=b0;
    }
}

// ---------------------------------------------------------------------------
// pair bias: pb[h][i][j] = LN(pair[i,j,:];ln_w,ln_b) @ w_pair[:,h] + INF*(mask[j]-1)
// one lane per (i,j) row; row kept in 128 VGPRs (fully static-indexed)
// ---------------------------------------------------------------------------
__global__ __launch_bounds__(256) void k_pair_bias(
    const float* __restrict__ pair, const float* __restrict__ wpc,
    const float* __restrict__ csb, const float* __restrict__ mask,
    float* __restrict__ pb)
{
    int row = blockIdx.x*256 + threadIdx.x;     // 0..N*N-1
    int j = row & (NN-1);
    const float* x = pair + (size_t)row*CPAIR;
    float y[128];
    float s=0.f, q=0.f;
    #pragma unroll
    for (int c4=0;c4<32;c4++){
        float4 v = *(const float4*)(x + 4*c4);
        y[4*c4]=v.x; y[4*c4+1]=v.y; y[4*c4+2]=v.z; y[4*c4+3]=v.w;
        s += v.x+v.y+v.z+v.w;
        q += v.x*v.x+v.y*v.y+v.z*v.z+v.w*v.w;
    }
    float mu = s*(1.f/128.f);
    float rs = rsqrtf(fmaxf(q*(1.f/128.f)-mu*mu,0.f)+1e-5f);
    float acc[16];
    #pragma unroll
    for (int h=0;h<16;h++) acc[h]=0.f;
    #pragma unroll
    for (int c=0;c<128;c++){
        float yc = y[c];
        const float4* wr = (const float4*)(wpc + c*16);
        float4 w0=wr[0], w1=wr[1], w2=wr[2], w3=wr[3];
        acc[0]+=yc*w0.x; acc[1]+=yc*w0.y; acc[2]+=yc*w0.z; acc[3]+=yc*w0.w;
        acc[4]+=yc*w1.x; acc[5]+=yc*w1.y; acc[6]+=yc*w1.z; acc[7]+=yc*w1.w;
        acc[8]+=yc*w2.x; acc[9]+=yc*w2.y; acc[10]+=yc*w2.z; acc[11]+=yc*w2.w;
        acc[12]+=yc*w3.x; acc[13]+=yc*w3.y; acc[14]+=yc*w3.z; acc[15]+=yc*w3.w;
    }
    float mb = 1e8f*(mask[j]-1.f);
    #pragma unroll
    for (int h=0;h<16;h++){
        float out = (acc[h]-mu*csb[h])*rs + csb[16+h] + mb;
        pb[((size_t)h<<20) + row] = out;
    }
}

// ---------------------------------------------------------------------------
// LDS-free f32 GEMM core: lane = output row, 16-col strip per thread.
// A row-major [2048,768], B row-major [768,768].
// ---------------------------------------------------------------------------
__device__ __forceinline__ void gemm_core16(const float* __restrict__ arow,
                                            const float* __restrict__ bbase,
                                            float acc[16])
{
    for (int k4=0;k4<DIMM;k4+=4){
        float4 a4 = *(const float4*)(arow+k4);
        float av[4]={a4.x,a4.y,a4.z,a4.w};
        #pragma unroll
        for (int kk=0;kk<4;kk++){
            const float* brow = bbase + (size_t)(k4+kk)*DIMM;
            float4 b0 = *(const float4*)(brow+0);
            float4 b1 = *(const float4*)(brow+4);
            float4 b2 = *(const float4*)(brow+8);
            float4 b3 = *(const float4*)(brow+12);
            float ak = av[kk];
            acc[0]+=ak*b0.x;  acc[1]+=ak*b0.y;  acc[2]+=ak*b0.z;  acc[3]+=ak*b0.w;
            acc[4]+=ak*b1.x;  acc[5]+=ak*b1.y;  acc[6]+=ak*b1.z;  acc[7]+=ak*b1.w;
            acc[8]+=ak*b2.x;  acc[9]+=ak*b2.y;  acc[10]+=ak*b2.z; acc[11]+=ak*b2.w;
            acc[12]+=ak*b3.x; acc[13]+=ak*b3.y; acc[14]+=ak*b3.z; acc[15]+=ak*b3.w;
        }
    }
}

// skip = s_ln @ skip_w
__global__ __launch_bounds__(256) void k_gemm_skip(
    const float* __restrict__ A, const float* __restrict__ B, float* __restrict__ C)
{
    int row = blockIdx.x*256 + threadIdx.x;
    int col0 = blockIdx.y*NSTRIP;
    float acc[16];
    #pragma unroll
    for (int i=0;i<16;i++) acc[i]=0.f;
    gemm_core16(A + (size_t)row*DIMM, B + col0, acc);
    float4* cp = (float4*)(C + (size_t)row*DIMM + col0);
    #pragma unroll
    for (int i=0;i<4;i++) cp[i] = make_float4(acc[4*i],acc[4*i+1],acc[4*i+2],acc[4*i+3]);
}

// a = sigmoid(s_ln@gate_w + gate_b) * a_ln + skip
__global__ __launch_bounds__(256) void k_gemm_gatecomb(
    const float* __restrict__ A, const float* __restrict__ B,
    const float* __restrict__ gb, const float* __restrict__ a_ln,
    const float* __restrict__ skip, float* __restrict__ outp)
{
    int row = blockIdx.x*256 + threadIdx.x;
    int col0 = blockIdx.y*NSTRIP;
    float acc[16];
    #pragma unroll
    for (int i=0;i<16;i++) acc[i]=0.f;
    gemm_core16(A + (size_t)row*DIMM, B + col0, acc);
    const float4* gb4 = (const float4*)(gb+col0);
    const float4* al4 = (const float4*)(a_ln + (size_t)row*DIMM + col0);
    const float4* sk4 = (const float4*)(skip + (size_t)row*DIMM + col0);
    float4* out4 = (float4*)(outp + (size_t)row*DIMM + col0);
    #pragma unroll
    for (int i=0;i<4;i++){
        float4 b=gb4[i], av=al4[i], sk=sk4[i], r;
        r.x = sigm(acc[4*i+0]+b.x)*av.x + sk.x;
        r.y = sigm(acc[4*i+1]+b.y)*av.y + sk.y;
        r.z = sigm(acc[4*i+2]+b.z)*av.z + sk.z;
        r.w = sigm(acc[4*i+3]+b.w)*av.w + sk.w;
        out4[i]=r;
    }
}

// q/k/v (permuted to [S,H,N,C], q scaled) and gate = sigmoid(a@w_gate+b_gate)
__global__ __launch_bounds__(256) void k_gemm_qkvg(
    const float* __restrict__ A,
    const float* __restrict__ wq, const float* __restrict__ wk,
    const float* __restrict__ wv, const float* __restrict__ wg,
    const float* __restrict__ bgate,
    float* __restrict__ qb, float* __restrict__ kb, float* __restrict__ vb,
    float* __restrict__ g)
{
    int row = blockIdx.x*256 + threadIdx.x;
    int col0 = blockIdx.y*NSTRIP;
    int z = blockIdx.z;
    const float* B = (z==0)?wq:(z==1)?wk:(z==2)?wv:wg;
    float acc[16];
    #pragma unroll
    for (int i=0;i<16;i++) acc[i]=0.f;
    gemm_core16(A + (size_t)row*DIMM, B + col0, acc);
    if (z==3){
        const float4* b4 = (const float4*)(bgate+col0);
        float4* out4 = (float4*)(g + (size_t)row*DIMM + col0);
        #pragma unroll
        for (int i=0;i<4;i++){
            float4 b=b4[i], r;
            r.x=sigm(acc[4*i+0]+b.x); r.y=sigm(acc[4*i+1]+b.y);
            r.z=sigm(acc[4*i+2]+b.z); r.w=sigm(acc[4*i+3]+b.w);
            out4[i]=r;
        }
    } else {
        float scale = (z==0)? 0.14433756729740643f : 1.f;   // 1/sqrt(48) for q
        int s = row>>10, n = row&(NN-1);
        int h = col0/CH, cc0 = col0 - h*CH;                  // 16-strip never straddles a head
        float* dst = ((z==0)?qb:(z==1)?kb:vb) + (((size_t)(s*HEADS+h)*NN + n)*CH + cc0);
        float4* d4 = (float4*)dst;
        #pragma unroll
        for (int i=0;i<4;i++)
            d4[i] = make_float4(acc[4*i]*scale,acc[4*i+1]*scale,acc[4*i+2]*scale,acc[4*i+3]*scale);
    }
}

// o2 = o_g @ wo + bo
__global__ __launch_bounds__(256) void k_gemm_wo(
    const float* __restrict__ A, const float* __restrict__ B,
    const float* __restrict__ bo, float* __restrict__ C)
{
    int row = blockIdx.x*256 + threadIdx.x;
    int col0 = blockIdx.y*NSTRIP;
    float acc[16];
    #pragma unroll
    for (int i=0;i<16;i++) acc[i]=0.f;
    gemm_core16(A + (size_t)row*DIMM, B + col0, acc);
    const float4* b4 = (const float4*)(bo+col0);
    float4* out4 = (float4*)(C + (size_t)row*DIMM + col0);
    #pragma unroll
    for (int i=0;i<4;i++){
        float4 b=b4[i];
        out4[i]=make_float4(acc[4*i]+b.x,acc[4*i+1]+b.y,acc[4*i+2]+b.z,acc[4*i+3]+b.w);
    }
}

// out = sigmoid(o2@w_out + b_out) * o2
__global__ __launch_bounds__(256) void k_gemm_out(
    const float* __restrict__ A, const float* __restrict__ B,
    const float* __restrict__ bout, float* __restrict__ C)
{
    int row = blockIdx.x*256 + threadIdx.x;
    int col0 = blockIdx.y*NSTRIP;
    float acc[16];
    #pragma unroll
    for (int i=0;i<16;i++) acc[i]=0.f;
    gemm_core16(A + (size_t)row*DIMM, B + col0, acc);
    const float4* b4 = (const float4*)(bout+col0);
    const float4* a4 = (const float4*)(A + (size_t)row*DIMM + col0);
    float4* out4 = (float4*)(C + (size_t)row*DIMM + col0);
    #pragma unroll
    for (int i=0;i<4;i++){
        float4 b=b4[i], av=a4[i], r;
        r.x=sigm(acc[4*i+0]+b.x)*av.x; r.y=sigm(acc[4*i+1]+b.y)*av.y;
        r.z=sigm(acc[4*i+2]+b.z)*av.z; r.w=sigm(acc[4*i+3]+b.w)*av.w;
        out4[i]=r;
    }
}

// ---------------------------------------------------------------------------
// flash attention, lane = q row, k-range split KSPLIT ways; softmax lane-local
// ---------------------------------------------------------------------------
__global__ __launch_bounds__(256) void k_attn(
    const float* __restrict__ qm, const float* __restrict__ km,
    const float* __restrict__ vm, const float* __restrict__ pb,
    float* __restrict__ pm, float* __restrict__ pl, float* __restrict__ po)
{
    int qrow = blockIdx.x*256 + threadIdx.x;       // 0..1023 (grid.x=4)
    int sh = blockIdx.y;                            // s*16+h
    int split = blockIdx.z;
    int h = sh & (HEADS-1);
    const float* qp = qm + ((size_t)sh*NN + qrow)*CH;
    float4 qv[12];
    #pragma unroll
    for (int i=0;i<12;i++) qv[i] = *(const float4*)(qp + 4*i);
    float4 o[12];
    #pragma unroll
    for (int i=0;i<12;i++) o[i] = make_float4(0.f,0.f,0.f,0.f);
    float m = -1e30f, l = 0.f;
    int k0 = split*(NN/KSPLIT);
    const float* pbrow = pb + ((size_t)h*NN*NN) + (size_t)qrow*NN + k0;
    const float* kbase = km + ((size_t)sh*NN + k0)*CH;
    const float* vbase = vm + ((size_t)sh*NN + k0)*CH;
    for (int kc=0; kc<NN/KSPLIT; kc+=KCH){
        float sc[KCH];
        #pragma unroll
        for (int j=0;j<KCH;j++){
            const float4* kr = (const float4*)(kbase + (size_t)(kc+j)*CH);
            float a0 = pbrow[kc+j];
            #pragma unroll
            for (int c=0;c<12;c++){
                float4 kv = kr[c];
                a0 += qv[c].x*kv.x + qv[c].y*kv.y + qv[c].z*kv.z + qv[c].w*kv.w;
            }
            sc[j]=a0;
        }
        float mc = m;
        #pragma unroll
        for (int j=0;j<KCH;j++) mc = fmaxf(mc, sc[j]);
        float corr = __expf(m - mc);
        m = mc;
        l *= corr;
        #pragma unroll
        for (int i=0;i<12;i++){ o[i].x*=corr; o[i].y*=corr; o[i].z*=corr; o[i].w*=corr; }
        #pragma unroll
        for (int j=0;j<KCH;j++){
            float p = __expf(sc[j]-mc);
            l += p;
            const float4* vr = (const float4*)(vbase + (size_t)(kc+j)*CH);
            #pragma unroll
            for (int c=0;c<12;c++){
                float4 vv = vr[c];
                o[c].x+=p*vv.x; o[c].y+=p*vv.y; o[c].z+=p*vv.z; o[c].w+=p*vv.w;
            }
        }
    }
    size_t idx = (size_t)split*32768 + (size_t)sh*NN + qrow;
    pm[idx]=m; pl[idx]=l;
    float4* pop = (float4*)(po + idx*CH);
    #pragma unroll
    for (int i=0;i<12;i++) pop[i]=o[i];
}

// combine k-splits, normalize, apply sigmoid gate, write o_g [2048,768]
__global__ __launch_bounds__(256) void k_combine(
    const float* __restrict__ pm, const float* __restrict__ pl,
    const float* __restrict__ po, const float* __restrict__ g,
    float* __restrict__ og)
{
    int gid = blockIdx.x*256+threadIdx.x;   // 32768*48 threads
    int row = gid / CH;                      // sh*N + qn
    int c = gid - row*CH;
    float mm = -1e30f;
    #pragma unroll
    for (int s=0;s<KSPLIT;s++) mm = fmaxf(mm, pm[s*32768+row]);
    float ls=0.f, os=0.f;
    #pragma unroll
    for (int s=0;s<KSPLIT;s++){
        float e = __expf(pm[s*32768+row]-mm);
        ls += pl[s*32768+row]*e;
        os += po[((size_t)s*32768+row)*CH + c]*e;
    }
    float oval = os/ls;
    int sh = row>>10; int qn = row & (NN-1);
    int s2 = sh>>4;   int hh = sh & 15;
    size_t orow = ((size_t)(s2*NN+qn))*DIMM + (size_t)hh*CH + c;
    og[orow] = oval * g[orow];
}

// ---------------------------------------------------------------------------
extern "C" void kernel_launch(void* const* d_in, const int* in_sizes, int n_in,
                              void* d_out, int out_size, void* d_ws, size_t ws_size,
                              hipStream_t stream)
{
    const float* srep   = (const float*)d_in[0];
    const float* sproj  = (const float*)d_in[1];
    const float* pair   = (const float*)d_in[2];
    const float* mask   = (const float*)d_in[3];
    const float* s_w    = (const float*)d_in[4];
    const float* gate_w = (const float*)d_in[5];
    const float* gate_b = (const float*)d_in[6];
    const float* skip_w = (const float*)d_in[7];
    const float* wq     = (const float*)d_in[8];
    const float* wk     = (const float*)d_in[9];
    const float* wv     = (const float*)d_in[10];
    const float* w_gate = (const float*)d_in[11];
    const float* b_gate = (const float*)d_in[12];
    const float* wo     = (const float*)d_in[13];
    const float* bo     = (const float*)d_in[14];
    const float* plnw   = (const float*)d_in[15];
    const float* plnb   = (const float*)d_in[16];
    const float* w_pair = (const float*)d_in[17];
    const float* w_out  = (const float*)d_in[18];
    const float* b_out  = (const float*)d_in[19];
    float* out = (float*)d_out;

    const size_t T = (size_t)NROWS*DIMM;   // 1572864
    float* w = (float*)d_ws;
    float* a_ln = w;                  // region0: a_ln,s_ln,skip,a  (4*T) — later aliased by po
    float* s_ln = a_ln + T;
    float* skip = s_ln + T;
    float* a    = skip + T;
    float* g    = w + 4*T;
    float* qb   = g + T;
    float* kb   = qb + T;
    float* vb   = kb + T;
    float* og   = vb + T;
    float* o2   = og + T;
    float* pbias= o2 + T;             // 16,777,216
    float* wpc  = pbias + (size_t)HEADS*NN*NN;
    float* csb  = wpc + 2048;         // 32
    float* pm   = csb + 32;           // KSPLIT*32768
    float* pl   = pm + KSPLIT*32768;
    float* po   = a_ln;               // alias: a_ln..a dead before attention; 4*T == KSPLIT*32768*48

    k_ln_single<<<NROWS, 256, 0, stream>>>(srep, sproj, s_w, a_ln, s_ln);
    k_pair_pre<<<1, 256, 0, stream>>>(plnw, plnb, w_pair, wpc, csb);
    k_pair_bias<<<(NN*NN)/256, 256, 0, stream>>>(pair, wpc, csb, mask, pbias);

    dim3 ggrid(NROWS/256, DIMM/NSTRIP);
    k_gemm_skip<<<ggrid, 256, 0, stream>>>(s_ln, skip_w, skip);
    k_gemm_gatecomb<<<ggrid, 256, 0, stream>>>(s_ln, gate_w, gate_b, a_ln, skip, a);
    k_gemm_qkvg<<<dim3(NROWS/256, DIMM/NSTRIP, 4), 256, 0, stream>>>(
        a, wq, wk, wv, w_gate, b_gate, qb, kb, vb, g);

    k_attn<<<dim3(NN/256, 2*HEADS, KSPLIT), 256, 0, stream>>>(qb, kb, vb, pbias, pm, pl, po);
    k_combine<<<(32768*CH)/256, 256, 0, stream>>>(pm, pl, po, g, og);

    k_gemm_wo<<<ggrid, 256, 0, stream>>>(og, wo, bo, o2);
    k_gemm_out<<<ggrid, 256, 0, stream>>>(o2, w_out, b_out, out);
}